// Round 13
// baseline (6511.491 us; speedup 1.0000x reference)
//
#include <hip/hip_runtime.h>
#include <math.h>

#define BB 64
#define SS 256
#define D_IN 400
#define D_RNN 200
#define HID 256
#define G4 1024   // 4*HID
#define KP 224    // K padded for MFMA (200 -> 224)

// workspace layout (float offsets)
#define OFF_WTLIN 0                              // [400][200] f32
#define OFF_WIH16 (OFF_WTLIN + 400*200)          // [2][1024][224] f16
#define OFF_WPACK (OFF_WIH16 + 2*1024*224/2)     // [2][32 chunk][1024 row][8 f16]
#define OFF_XH16  (OFF_WPACK + 2*1024*256/2)     // [2][16384 tok][224] f16
#define OFF_GX    (OFF_XH16 + 2*16384*224/2)     // [2][16384][1024] f32

typedef _Float16 half2_t __attribute__((ext_vector_type(2)));
typedef _Float16 f16x8 __attribute__((ext_vector_type(8)));
typedef float f32x4 __attribute__((ext_vector_type(4)));

__device__ __forceinline__ half2_t u2h(unsigned u) {
    union { unsigned u; half2_t h; } x; x.u = u; return x.h;
}

__device__ __forceinline__ float dot2acc(unsigned hu, unsigned wu, float acc) {
#if __has_builtin(__builtin_amdgcn_fdot2)
    return __builtin_amdgcn_fdot2(u2h(hu), u2h(wu), acc, false);
#else
    half2_t h = u2h(hu), w = u2h(wu);
    acc = fmaf((float)h.x, (float)w.x, acc);
    acc = fmaf((float)h.y, (float)w.y, acc);
    return acc;
#endif
}

__device__ __forceinline__ unsigned packf16(float a, float b) {
    union { _Float16 h[2]; unsigned u; } x;
    x.h[0] = (_Float16)a; x.h[1] = (_Float16)b;
    return x.u;
}

__device__ __forceinline__ float sigm_f(float x) {
    return 1.0f / (1.0f + __expf(-x));
}
__device__ __forceinline__ float tanh_f(float x) {
    return 2.0f / (1.0f + __expf(-2.0f * x)) - 1.0f;
}

// ---------------- packs ----------------
__global__ void kt_wlin(const float* __restrict__ W, float* __restrict__ Wt) {
    int id = blockIdx.x * 256 + threadIdx.x;
    if (id >= D_RNN * D_IN) return;
    int j = id / D_IN, k = id % D_IN;
    Wt[k * D_RNN + j] = W[id];
}

// Wih f32 [1024][200] -> f16 [dir][n][224] zero-padded (B operand, n-major)
__global__ void kt_wih16p(const float* __restrict__ Wl, const float* __restrict__ Wr,
                          _Float16* __restrict__ Wp) {
    int id = blockIdx.x * 256 + threadIdx.x;
    if (id >= 2 * 1024 * KP) return;
    int dir = id / (1024 * KP);
    int rem = id % (1024 * KP);
    int n = rem / KP, k = rem % KP;
    const float* src = dir ? Wr : Wl;
    Wp[id] = (k < D_RNN) ? (_Float16)src[n * D_RNN + k] : (_Float16)0.0f;
}

// Whh f32 [row][k] -> f16 packed chunk-major: wpack[dir][k/8][row][k%8]  (r5 layout)
__global__ void kt_wpack(const float* __restrict__ Wl, const float* __restrict__ Wr,
                         _Float16* __restrict__ Wp) {
    int id = blockIdx.x * 256 + threadIdx.x;
    if (id >= 2 * G4 * HID) return;
    int dir = id / (G4 * HID);
    int rem = id % (G4 * HID);
    int r = rem / HID, k = rem % HID;
    const float* src = dir ? Wr : Wl;
    Wp[(((size_t)dir * 32 + (k >> 3)) * G4 + r) * 8 + (k & 7)] = (_Float16)src[rem];
}

// ---------------- K1: embeddings + concat + linear + tanh -> f16 x (padded 224) ----------------
__launch_bounds__(512)
__global__ void k_embed_linear(const int* __restrict__ ci, const int* __restrict__ bli,
                               const int* __restrict__ bri, const int* __restrict__ sci,
                               const int* __restrict__ sbli, const int* __restrict__ sbri,
                               const float* __restrict__ ce, const float* __restrict__ be,
                               const float* __restrict__ sce, const float* __restrict__ sbe,
                               const float* __restrict__ Wt, const float* __restrict__ blin,
                               _Float16* __restrict__ xh) {
    __shared__ __align__(16) float vec[16][2][D_IN];
    __shared__ int idx[16][6];
    int tid = threadIdx.x;
    int g0 = blockIdx.x * 16;

    if (tid < 96) {
        int tt = tid / 6, w = tid % 6;
        int g = g0 + tt;
        const int* arr = (w == 0) ? ci : (w == 1) ? sci : (w == 2) ? bli
                         : (w == 3) ? bri : (w == 4) ? sbli : sbri;
        idx[tt][w] = arr[g];
    }
    __syncthreads();

    for (int v = tid; v < 16 * D_IN; v += 512) {
        int tt = v / D_IN, p = v % D_IN;
        float lv, rv;
        if (p < 100)      { float e = ce[idx[tt][0] * 100 + p];          lv = rv = e; }
        else if (p < 200) { float e = sce[idx[tt][1] * 100 + (p - 100)]; lv = rv = e; }
        else if (p < 300) { int q = p - 200;
                            lv = be[idx[tt][2] * 100 + q];
                            rv = be[idx[tt][3] * 100 + q]; }
        else              { int q = p - 300;
                            lv = sbe[idx[tt][4] * 100 + q];
                            rv = sbe[idx[tt][5] * 100 + q]; }
        vec[tt][0][p] = lv;
        vec[tt][1][p] = rv;
    }
    __syncthreads();

    if (tid < 400) {
        int side = tid / 200, j = tid % 200;
        float acc[16];
        #pragma unroll
        for (int t = 0; t < 16; t++) acc[t] = 0.0f;

        for (int k4 = 0; k4 < D_IN / 4; k4++) {
            float w0 = Wt[(4 * k4 + 0) * D_RNN + j];
            float w1 = Wt[(4 * k4 + 1) * D_RNN + j];
            float w2 = Wt[(4 * k4 + 2) * D_RNN + j];
            float w3 = Wt[(4 * k4 + 3) * D_RNN + j];
            #pragma unroll
            for (int t = 0; t < 16; t++) {
                float4 xv = *(const float4*)&vec[t][side][4 * k4];
                acc[t] += xv.x * w0 + xv.y * w1 + xv.z * w2 + xv.w * w3;
            }
        }
        float bias = blin[j];
        #pragma unroll
        for (int t = 0; t < 16; t++) {
            int g = g0 + t;
            int b = g >> 8, s = g & 255;
            size_t row = (size_t)(side * BB + b) * SS + s;
            xh[row * KP + j] = (_Float16)tanh_f(acc[t] + bias);
        }
    } else if (tid < 448) {
        // zero-fill K padding [200,224)
        int side = (tid - 400) / 24;
        int j = 200 + (tid - 400) % 24;
        #pragma unroll
        for (int t = 0; t < 16; t++) {
            int g = g0 + t;
            int b = g >> 8, s = g & 255;
            size_t row = (size_t)(side * BB + b) * SS + s;
            xh[row * KP + j] = (_Float16)0.0f;
        }
    }
}

// ---------------- K2: gate-x GEMM via MFMA 16x16x32 f16 ----------------
// Block: 64 tokens x 256 cols; 4 waves, each wave 16 tokens x 256 cols (16 n-frags).
// A: xh[tok][224] row-major; B: wih[dir][n][224] n-major. D=A*B, f32 accum.
__launch_bounds__(256)
__global__ void k_gatex_mfma(const _Float16* __restrict__ xh,
                             const _Float16* __restrict__ wih,
                             const float* __restrict__ bihl, const float* __restrict__ bhhl,
                             const float* __restrict__ bihr, const float* __restrict__ bhhr,
                             float* __restrict__ gx) {
    int bid = blockIdx.x;                 // 2048 = 512 m-tiles x 4 n-tiles
    int nt = bid & 3, mt = bid >> 2;
    int tid = threadIdx.x;
    int w = tid >> 6, lane = tid & 63;
    int lrow = lane & 15, lk = lane >> 4;
    int TB = mt * 64 + w * 16;            // token base for this wave
    int dir = (TB >= 16384) ? 1 : 0;
    int NB = nt * 256;

    const _Float16* wp = wih + (size_t)dir * 1024 * KP;
    const float* bih = dir ? bihr : bihl;
    const float* bhh = dir ? bhhr : bhhl;

    float bias[16];
    #pragma unroll
    for (int f = 0; f < 16; f++) {
        int col = NB + f * 16 + lrow;
        bias[f] = bih[col] + bhh[col];
    }

    f32x4 acc[16];
    #pragma unroll
    for (int f = 0; f < 16; f++) acc[f] = (f32x4){0.f, 0.f, 0.f, 0.f};

    const _Float16* arow = xh + (size_t)(TB + lrow) * KP + lk * 8;
    for (int kst = 0; kst < KP / 32; kst++) {
        f16x8 a = *(const f16x8*)(arow + kst * 32);
        #pragma unroll
        for (int f = 0; f < 16; f++) {
            const _Float16* bp = wp + (size_t)(NB + f * 16 + lrow) * KP + kst * 32 + lk * 8;
            f16x8 b = *(const f16x8*)bp;
            acc[f] = __builtin_amdgcn_mfma_f32_16x16x32_f16(a, b, acc[f], 0, 0, 0);
        }
    }

    // D layout: col = lane&15, row = (lane>>4)*4 + i
    float* gbase = gx + (size_t)TB * G4 + NB;
    #pragma unroll
    for (int f = 0; f < 16; f++) {
        #pragma unroll
        for (int i = 0; i < 4; i++) {
            int row = lk * 4 + i;
            gbase[(size_t)row * G4 + f * 16 + lrow] = acc[f][i] + bias[f];
        }
    }
}

// ---------------- K3: LSTM (r5-proven, 449 us). One block per (dir,b), 512 thr.
// Thread (c=t&255, kh=t>>8) computes gate rows {c,c+256,c+512,c+768} over
// K-half [kh*128, kh*128+128). kh=1 exports partials via LDS; kh=0 finalizes.
__global__ void
__attribute__((amdgpu_flat_work_group_size(512, 512), amdgpu_waves_per_eu(2, 2)))
k_lstm(const _Float16* __restrict__ wpack, const float* __restrict__ gx,
       float* __restrict__ out) {
    __shared__ __align__(16) uint4 wlds[16][512];      // 131072 B
    __shared__ __align__(16) float4 exv[256];          // 4096 B
    __shared__ __align__(16) unsigned hbits[2][128];   // 1024 B (256 f16 x2)

    int t = threadIdx.x;
    int c = t & 255, kh = t >> 8;
    int bid = blockIdx.x;           // 128
    int dir = bid >> 6, b = bid & 63;

    // ---- weight load (coalesced, chunk-major pack) ----
    const uint4* wp = reinterpret_cast<const uint4*>(wpack) + (size_t)dir * 32 * G4 / 2 * 2;
    wp = reinterpret_cast<const uint4*>(wpack) + (size_t)dir * 32 * G4;
    uint4 wreg[4][12];
    #pragma unroll
    for (int g = 0; g < 4; g++)
        #pragma unroll
        for (int i = 0; i < 12; i++)
            wreg[g][i] = wp[(kh * 16 + i) * G4 + g * 256 + c];
    #pragma unroll
    for (int g = 0; g < 4; g++)
        #pragma unroll
        for (int i = 0; i < 12; i++)
            asm volatile("" : "+v"(wreg[g][i].x), "+v"(wreg[g][i].y),
                              "+v"(wreg[g][i].z), "+v"(wreg[g][i].w));
    #pragma unroll
    for (int g = 0; g < 4; g++)
        #pragma unroll
        for (int i2 = 0; i2 < 4; i2++)
            wlds[g * 4 + i2][t] = wp[(kh * 16 + 12 + i2) * G4 + g * 256 + c];

    const float* gxp = gx + (size_t)(dir * BB + b) * SS * G4;
    float* outp = out + (size_t)b * SS * (2 * HID) + dir * HID + c;
    unsigned short* hsafe = nullptr; (void)hsafe;

    if (t < 128) { hbits[0][t] = 0u; hbits[1][t] = 0u; }
    float cst = 0.0f;
    __syncthreads();

    int ts = dir ? (SS - 1) : 0;
    int dstep = dir ? -1 : 1;
    float gxc[4];
    if (kh == 0) {
        const float* g0p = gxp + (size_t)ts * G4;
        #pragma unroll
        for (int g = 0; g < 4; g++) gxc[g] = g0p[g * 256 + c];
    }

    for (int s = 0; s < SS; s++) {
        int par = s & 1;

        const uint4* h4 = reinterpret_cast<const uint4*>(hbits[par]);
        float a0, a1, a2, a3;
        if (kh == 0) { a0 = gxc[0]; a1 = gxc[1]; a2 = gxc[2]; a3 = gxc[3]; }
        else         { a0 = a1 = a2 = a3 = 0.0f; }

        #pragma unroll
        for (int i = 0; i < 12; i++) {
            uint4 hh = h4[kh * 16 + i];
            a0 = dot2acc(hh.x, wreg[0][i].x, a0); a0 = dot2acc(hh.y, wreg[0][i].y, a0);
            a0 = dot2acc(hh.z, wreg[0][i].z, a0); a0 = dot2acc(hh.w, wreg[0][i].w, a0);
            a1 = dot2acc(hh.x, wreg[1][i].x, a1); a1 = dot2acc(hh.y, wreg[1][i].y, a1);
            a1 = dot2acc(hh.z, wreg[1][i].z, a1); a1 = dot2acc(hh.w, wreg[1][i].w, a1);
            a2 = dot2acc(hh.x, wreg[2][i].x, a2); a2 = dot2acc(hh.y, wreg[2][i].y, a2);
            a2 = dot2acc(hh.z, wreg[2][i].z, a2); a2 = dot2acc(hh.w, wreg[2][i].w, a2);
            a3 = dot2acc(hh.x, wreg[3][i].x, a3); a3 = dot2acc(hh.y, wreg[3][i].y, a3);
            a3 = dot2acc(hh.z, wreg[3][i].z, a3); a3 = dot2acc(hh.w, wreg[3][i].w, a3);
        }
        #pragma unroll
        for (int i2 = 0; i2 < 4; i2++) {
            uint4 hh = h4[kh * 16 + 12 + i2];
            uint4 v0 = wlds[0 * 4 + i2][t];
            uint4 v1 = wlds[1 * 4 + i2][t];
            uint4 v2 = wlds[2 * 4 + i2][t];
            uint4 v3 = wlds[3 * 4 + i2][t];
            a0 = dot2acc(hh.x, v0.x, a0); a0 = dot2acc(hh.y, v0.y, a0);
            a0 = dot2acc(hh.z, v0.z, a0); a0 = dot2acc(hh.w, v0.w, a0);
            a1 = dot2acc(hh.x, v1.x, a1); a1 = dot2acc(hh.y, v1.y, a1);
            a1 = dot2acc(hh.z, v1.z, a1); a1 = dot2acc(hh.w, v1.w, a1);
            a2 = dot2acc(hh.x, v2.x, a2); a2 = dot2acc(hh.y, v2.y, a2);
            a2 = dot2acc(hh.z, v2.z, a2); a2 = dot2acc(hh.w, v2.w, a2);
            a3 = dot2acc(hh.x, v3.x, a3); a3 = dot2acc(hh.y, v3.y, a3);
            a3 = dot2acc(hh.z, v3.z, a3); a3 = dot2acc(hh.w, v3.w, a3);
        }

        // kh=0 prefetches next step's gx while the exchange happens
        float ngx[4] = {0.f, 0.f, 0.f, 0.f};
        if (kh == 0 && s < SS - 1) {
            const float* gn = gxp + (size_t)(ts + dstep) * G4;
            #pragma unroll
            for (int g = 0; g < 4; g++) ngx[g] = gn[g * 256 + c];
        }

        if (kh == 1) exv[c] = make_float4(a0, a1, a2, a3);
        __syncthreads();

        if (kh == 0) {
            float4 p = exv[c];
            float ig = sigm_f(a0 + p.x);
            float fg = sigm_f(a1 + p.y);
            float gg = tanh_f(a2 + p.z);
            float og = sigm_f(a3 + p.w);
            cst = fg * cst + ig * gg;
            float hv = og * tanh_f(cst);
            outp[(size_t)ts * (2 * HID)] = hv;
            reinterpret_cast<unsigned short*>(hbits[par ^ 1])[c] =
                __builtin_bit_cast(unsigned short, (_Float16)hv);
            #pragma unroll
            for (int g = 0; g < 4; g++) gxc[g] = ngx[g];
        }
        __syncthreads();

        ts += dstep;
    }
}

extern "C" void kernel_launch(void* const* d_in, const int* in_sizes, int n_in,
                              void* d_out, int out_size, void* d_ws, size_t ws_size,
                              hipStream_t stream) {
    const int* char_features      = (const int*)d_in[0];
    const int* bichar_left        = (const int*)d_in[1];
    const int* bichar_right       = (const int*)d_in[2];
    const int* static_char        = (const int*)d_in[3];
    const int* static_bichar_left = (const int*)d_in[4];
    const int* static_bichar_right= (const int*)d_in[5];
    const float* char_emb         = (const float*)d_in[6];
    const float* bichar_emb       = (const float*)d_in[7];
    const float* static_char_emb  = (const float*)d_in[8];
    const float* static_bichar_emb= (const float*)d_in[9];
    const float* W_lin            = (const float*)d_in[10];
    const float* b_lin            = (const float*)d_in[11];
    const float* Wih_l            = (const float*)d_in[12];
    const float* Whh_l            = (const float*)d_in[13];
    const float* bih_l            = (const float*)d_in[14];
    const float* bhh_l            = (const float*)d_in[15];
    const float* Wih_r            = (const float*)d_in[16];
    const float* Whh_r            = (const float*)d_in[17];
    const float* bih_r            = (const float*)d_in[18];
    const float* bhh_r            = (const float*)d_in[19];

    float* ws    = (float*)d_ws;
    float* wtlin = ws + OFF_WTLIN;
    _Float16* wih16 = (_Float16*)(ws + OFF_WIH16);
    _Float16* wpack = (_Float16*)(ws + OFF_WPACK);
    _Float16* xh16  = (_Float16*)(ws + OFF_XH16);
    float* gxbuf = ws + OFF_GX;
    float* out   = (float*)d_out;

    kt_wlin<<<(D_RNN * D_IN + 255) / 256, 256, 0, stream>>>(W_lin, wtlin);
    kt_wih16p<<<(2 * 1024 * KP + 255) / 256, 256, 0, stream>>>(Wih_l, Wih_r, wih16);
    kt_wpack<<<(2 * G4 * HID + 255) / 256, 256, 0, stream>>>(Whh_l, Whh_r, wpack);

    k_embed_linear<<<(BB * SS) / 16, 512, 0, stream>>>(
        char_features, bichar_left, bichar_right, static_char,
        static_bichar_left, static_bichar_right,
        char_emb, bichar_emb, static_char_emb, static_bichar_emb,
        wtlin, b_lin, xh16);

    k_gatex_mfma<<<2048, 256, 0, stream>>>(
        xh16, wih16, bih_l, bhh_l, bih_r, bhh_r, gxbuf);

    k_lstm<<<2 * BB, 512, 0, stream>>>(wpack, gxbuf, out);
}